// Round 7
// baseline (133.465 us; speedup 1.0000x reference)
//
#include <hip/hip_runtime.h>
#include <hip/hip_bf16.h>

// feature [B=128, E=64, D=128] fp32 -> N = 8192 rows of dim 128.
// loss = mean_r( log(den_r) - log(pos_r) ),
//   den_r = sum_c exp(10*<f_r,f_c>), pos_r = sum over c in r's 64-row block.
#define N_ROWS 8192
#define DIM    128
#define EXPTEN 22026.465794806718f  // exp(10.0)
// Xb = normalize(f) * SCALE, SCALE^2 = 10*log2(e); then exp2(dot) = exp(10*<f,f>)
#define SCALE  3.7982826f

typedef __attribute__((ext_vector_type(8))) short short8;   // 8 bf16 = 4 VGPRs
typedef __attribute__((ext_vector_type(4))) float floatx4;  // MFMA C/D

#define EXP2F(x) __builtin_amdgcn_exp2f(x)

// async global->LDS DMA, 16B per lane; LDS dest = wave-uniform base + lane*16
#define GLOAD_LDS(g, l)                                                        \
    __builtin_amdgcn_global_load_lds(                                          \
        (const __attribute__((address_space(1))) void*)(g),                    \
        (__attribute__((address_space(3))) void*)(l), 16, 0, 0)

// ---- Kernel 1: L2-normalize rows, scale, cast to bf16; zero pos/den ----
__global__ void norm_kernel(const float* __restrict__ F, __hip_bfloat16* __restrict__ Xb,
                            float* __restrict__ pos, float* __restrict__ den) {
    int lane = threadIdx.x & 63;
    int wave = threadIdx.x >> 6;
    int row  = blockIdx.x * 4 + wave;           // 2048 blocks x 4 waves = 8192 rows
    const float2 v = *(const float2*)(F + (size_t)row * DIM + lane * 2);
    float ss = v.x * v.x + v.y * v.y;
    #pragma unroll
    for (int m = 1; m < 64; m <<= 1) ss += __shfl_xor(ss, m);
    float inv = rsqrtf(ss) * SCALE;
    __hip_bfloat162 o;
    o.x = __float2bfloat16(v.x * inv);
    o.y = __float2bfloat16(v.y * inv);
    *((__hip_bfloat162*)(Xb + (size_t)row * DIM) + lane) = o;
    if (lane == 0) { pos[row] = 0.f; den[row] = 0.f; }
}

// ---- Kernel 2: fused gram + exp + row sums ----
// r3 structure (best measured) with 50% more occupancy:
//   Block tile 256 rows x 64 cols/step. 4 waves; wave w owns rows
//   [rb*256+w*64, +64) x all 64 cols -> 64x64 subtile = 4x4 MFMA 16x16x32,
//   64 MFMA + 16 ds_read_b128 per barrier (r3's amortization; r5's 32/barrier
//   regressed). B-step = 64 cols x 128 K = 16 KB, double-buffered = 32 KB LDS
//   (r3 used 64 KB -> 2 blocks/CU; now 3 blocks/CU, 12 waves/CU).
//   A fragments register-resident (64 VGPRs, direct global loads, L2-hit).
//   Async global_load_lds staging + XOR swizzle folded into global source
//   addresses -> ds_read_b128 reads bank-conflict-free (0 measured r3-r5).
//   Atomics kept rare: 24 per den row + 1 per pos row = 205k total
//   (r6's 1.3M per-lane atomics caused 20.8 MB WRITE_SIZE and 2x regression).
// Grid 32 x 24 = 768 blocks = exactly 3/CU, one residency wave, no tail.
// launch_bounds(256,3): cap 170 VGPR >= ~165 needed; (256,4)'s 128 cap
// spilled catastrophically in r4 -- watch WRITE_SIZE for spill signature.
__global__ __launch_bounds__(256, 3) void gram_kernel(
        const __hip_bfloat16* __restrict__ Xb,
        float* __restrict__ pos, float* __restrict__ den) {
    __shared__ __hip_bfloat16 Bs[2][64 * DIM];   // 2 x 16 KB
    const int tid  = threadIdx.x;
    const int rb   = blockIdx.x;      // 0..31   rows [rb*256, +256)
    const int cg   = blockIdx.y;      // 0..23   col-tile group
    const int lane = tid & 63;
    const int wave = tid >> 6;        // row-64 strip within the 256-row tile
    const int quad = lane >> 4;       // 0..3
    const int l15  = lane & 15;       // 0..15

    // col-tile partition: 16 groups x 5 + 8 groups x 6 = 128 tiles of 64 cols
    const int start = (cg < 16) ? cg * 5 : 80 + (cg - 16) * 6;
    const int cnt   = (cg < 16) ? 5 : 6;

    // A fragments: rows rb*256+wave*64+mi*16+l15, elems ko*32+quad*8 (one-time).
    short8 af[4][4];
    {
        const __hip_bfloat16* Ab =
            Xb + ((size_t)(rb * 256 + wave * 64 + l15)) * DIM + quad * 8;
        #pragma unroll
        for (int mi = 0; mi < 4; ++mi)
            #pragma unroll
            for (int ko = 0; ko < 4; ++ko)
                af[mi][ko] = *(const short8*)(Ab + mi * 16 * DIM + ko * 32);
    }

    float dp[4][4];
    #pragma unroll
    for (int a = 0; a < 4; ++a)
        #pragma unroll
        for (int b = 0; b < 4; ++b) dp[a][b] = 0.f;

    // Stage 64-col tile ct into Bs[buf]: 1024 16B-chunks, 4 issues/thread.
    // LDS chunk j holds global chunk (j&15)^(c&15) of col-row c = j>>4.
    auto stage = [&](int ct, int buf) {
        #pragma unroll
        for (int i = 0; i < 4; ++i) {
            int chunk = (i * 4 + wave) * 64 + lane;   // 0..1023
            int c  = chunk >> 4;                       // 0..63
            int cs = (chunk & 15) ^ (c & 15);
            const __hip_bfloat16* gp = Xb + ((size_t)(ct * 64 + c)) * DIM + cs * 8;
            char* lp = (char*)&Bs[buf][0] + (i * 4 + wave) * 1024;  // wave-uniform
            GLOAD_LDS(gp, lp);
        }
    };

    auto compute = [&](int ct, int buf) {
        floatx4 acc[4][4];
        #pragma unroll
        for (int mi = 0; mi < 4; ++mi)
            #pragma unroll
            for (int ni = 0; ni < 4; ++ni) acc[mi][ni] = (floatx4)0.0f;

        const char* Bb = (const char*)&Bs[buf][0];
        #pragma unroll
        for (int ko = 0; ko < 4; ++ko) {
            short8 bf[4];
            #pragma unroll
            for (int ni = 0; ni < 4; ++ni) {
                int c  = ni * 16 + l15;               // c & 15 == l15
                int ch = (ko * 4 + quad) ^ l15;       // undo staging swizzle
                bf[ni] = *(const short8*)(Bb + c * 256 + ch * 16);
            }
            #pragma unroll
            for (int mi = 0; mi < 4; ++mi)
                #pragma unroll
                for (int ni = 0; ni < 4; ++ni)
                    acc[mi][ni] = __builtin_amdgcn_mfma_f32_16x16x32_bf16(
                        af[mi][ko], bf[ni], acc[mi][ni], 0, 0, 0);
        }

        // pos tile for this wave's 64 rows is global col-tile rb*4+wave;
        // wave-uniform predicate, true in exactly one block per wave.
        const bool pos_tile = (ct == rb * 4 + wave);
        #pragma unroll
        for (int mi = 0; mi < 4; ++mi)
            #pragma unroll
            for (int rg = 0; rg < 4; ++rg) {
                float dadd = 0.f;
                #pragma unroll
                for (int ni = 0; ni < 4; ++ni)
                    dadd += EXP2F(acc[mi][ni][rg]);
                if (pos_tile) {
                    // diagonal element: ni==mi, col l15 == row quad*4+rg;
                    // replace bf16-noisy exp(10*||x||^2) with exact exp(10).
                    if (l15 == quad * 4 + rg)
                        dadd += EXPTEN - EXP2F(acc[mi][mi][rg]);
                    float p = dadd;
                    #pragma unroll
                    for (int m = 1; m < 16; m <<= 1) p += __shfl_xor(p, m);
                    if (l15 == 0)
                        atomicAdd(&pos[rb * 256 + wave * 64 + mi * 16 + quad * 4 + rg], p);
                }
                dp[mi][rg] += dadd;
            }
    };

    stage(start, 0);
    __syncthreads();                       // drains stage(0) + A loads
    #pragma unroll 1
    for (int t = 0; t < cnt - 1; ++t) {
        stage(start + t + 1, (t + 1) & 1);  // async; drains at loop-end barrier
        compute(start + t, t & 1);          // 64 MFMA + epilogue covers latency
        __syncthreads();
    }
    compute(start + cnt - 1, (cnt - 1) & 1);

    // den: reduce across the 16 l15 lanes of each quad group, 1 atomic per row.
    #pragma unroll
    for (int mi = 0; mi < 4; ++mi)
        #pragma unroll
        for (int rg = 0; rg < 4; ++rg) {
            float d = dp[mi][rg];
            #pragma unroll
            for (int m = 1; m < 16; m <<= 1) d += __shfl_xor(d, m);
            if (l15 == 0)
                atomicAdd(&den[rb * 256 + wave * 64 + mi * 16 + quad * 4 + rg], d);
        }
}

// ---- Kernel 3: loss = mean(log(den/pos)) ----
__global__ void loss_kernel(const float* __restrict__ pos, const float* __restrict__ den,
                            float* __restrict__ out) {
    __shared__ float red[4];
    float acc = 0.f;
    for (int ii = threadIdx.x; ii < N_ROWS / 4; ii += 256) {
        float4 dv = ((const float4*)den)[ii];
        float4 pv = ((const float4*)pos)[ii];
        acc += __logf(dv.x / pv.x) + __logf(dv.y / pv.y) +
               __logf(dv.z / pv.z) + __logf(dv.w / pv.w);
    }
    #pragma unroll
    for (int m = 1; m < 64; m <<= 1) acc += __shfl_xor(acc, m);
    int lane = threadIdx.x & 63, w = threadIdx.x >> 6;
    if (lane == 0) red[w] = acc;
    __syncthreads();
    if (threadIdx.x == 0)
        out[0] = (red[0] + red[1] + red[2] + red[3]) * (1.0f / (float)N_ROWS);
}

extern "C" void kernel_launch(void* const* d_in, const int* in_sizes, int n_in,
                              void* d_out, int out_size, void* d_ws, size_t ws_size,
                              hipStream_t stream) {
    const float* feature = (const float*)d_in[0];
    // ws layout: pos[8192] f32 | den[8192] f32 | Xb[8192*128] bf16
    float* pos = (float*)d_ws;
    float* den = pos + N_ROWS;
    __hip_bfloat16* Xb = (__hip_bfloat16*)(den + N_ROWS);

    norm_kernel<<<N_ROWS / 4, 256, 0, stream>>>(feature, Xb, pos, den);
    gram_kernel<<<dim3(32, 24), 256, 0, stream>>>(Xb, pos, den);
    loss_kernel<<<1, 256, 0, stream>>>(pos, den, (float*)d_out);
}

// Round 8
// 101.363 us; speedup vs baseline: 1.3167x; 1.3167x over previous
//
#include <hip/hip_runtime.h>
#include <hip/hip_bf16.h>

// feature [B=128, E=64, D=128] fp32 -> N = 8192 rows of dim 128.
// loss = mean_r( log(den_r) - log(pos_r) ),
//   den_r = sum_c exp(10*<f_r,f_c>), pos_r = sum over c in r's 64-row block.
//
// r3-r7 lesson: the barrier'd LDS double-buffer structure is register-boxed
// (64-MFMA amortization needs ~190 regs -> only 2 waves/SIMD; 3 waves/SIMD
// forces spill (r4,r7: 50+ MB scratch WRITE_SIZE) or 32-MFMA barriers (r5,
// regressed)). r6: per-lane atomics = 20.8 MB memory-side traffic, 2x loss.
// This version: NO LDS, NO barriers, NO atomics. B streamed through
// registers in 16-col steps with explicit prefetch; per-row partials to
// plain stores; two tiny reduction kernels finish.
#define N_ROWS 8192
#define DIM    128
#define NGRP   24
#define EXPTEN 22026.465794806718f  // exp(10.0)
// Xb = normalize(f) * SCALE, SCALE^2 = 10*log2(e); then exp2(dot) = exp(10*<f,f>)
#define SCALE  3.7982826f

typedef __attribute__((ext_vector_type(8))) short short8;   // 8 bf16 = 4 VGPRs
typedef __attribute__((ext_vector_type(4))) float floatx4;  // MFMA C/D

#define EXP2F(x) __builtin_amdgcn_exp2f(x)

// ---- Kernel 1: L2-normalize rows, scale, cast to bf16 ----
__global__ void norm_kernel(const float* __restrict__ F, __hip_bfloat16* __restrict__ Xb) {
    int lane = threadIdx.x & 63;
    int wave = threadIdx.x >> 6;
    int row  = blockIdx.x * 4 + wave;           // 2048 blocks x 4 waves = 8192 rows
    const float2 v = *(const float2*)(F + (size_t)row * DIM + lane * 2);
    float ss = v.x * v.x + v.y * v.y;
    #pragma unroll
    for (int m = 1; m < 64; m <<= 1) ss += __shfl_xor(ss, m);
    float inv = rsqrtf(ss) * SCALE;
    __hip_bfloat162 o;
    o.x = __float2bfloat16(v.x * inv);
    o.y = __float2bfloat16(v.y * inv);
    *((__hip_bfloat162*)(Xb + (size_t)row * DIM) + lane) = o;
}

// ---- Kernel 2: fused gram + exp + row partial sums (LDS-free) ----
// Block (rb, cg): rows [rb*256,+256), col group cg (5 or 6 64-col tiles;
// 16x5 + 8x6 = 128 tiles). Grid 32x24 = 768 blocks = exactly 3/CU.
// Wave w owns 64 rows (af[4][4] = 64 VGPRs, loaded once from L2-resident Xb)
// and sweeps the group's cols 16 at a time: per step 4 b128 loads (prefetched
// one step ahead), 16 MFMA 16x16x32, 16 exp2 + adds. No synchronization of
// any kind; 12 waves/CU of pure TLP hide load latency.
// Output: part[cg*8192 + row] = this group's contribution to den[row]
// (plain store, single writer); pos[row] written by the unique group owning
// the row's diagonal 64x64 block.
// Register budget ~160 <= 168 cap of (256,3): af64 nb16 cb16 acc16 dp16 pp16
// + addressing. (r4/r7 spilled at ~180/cap168 and ~190/cap128 -> 2x loss;
// spill signature = WRITE_SIZE tens of MB.)
__global__ __launch_bounds__(256, 3) void gram_kernel(
        const __hip_bfloat16* __restrict__ Xb,
        float* __restrict__ pos, float* __restrict__ part) {
    const int rb   = blockIdx.x;      // 0..31
    const int cg   = blockIdx.y;      // 0..23
    const int lane = threadIdx.x & 63;
    const int wave = threadIdx.x >> 6;
    const int quad = lane >> 4;       // 0..3
    const int l15  = lane & 15;       // 0..15

    const int start  = (cg < 16) ? cg * 5 : 80 + (cg - 16) * 6;  // first 64-col tile
    const int cnt    = (cg < 16) ? 5 : 6;
    const int nsteps = cnt * 4;                                   // 16-col steps
    const int c0     = start * 64;

    const int R0 = rb * 256 + wave * 64;   // this wave's row base

    // A fragments: rows R0+mi*16+l15, k = ko*32+quad*8 (one-time, 16 x b128).
    short8 af[4][4];
    {
        const __hip_bfloat16* Ab = Xb + (size_t)(R0 + l15) * DIM + quad * 8;
        #pragma unroll
        for (int mi = 0; mi < 4; ++mi)
            #pragma unroll
            for (int ko = 0; ko < 4; ++ko)
                af[mi][ko] = *(const short8*)(Ab + mi * 16 * DIM + ko * 32);
    }

    // B stream: step s covers cols c0+s*16 .. +16; lane loads col c0+s*16+l15.
    const __hip_bfloat16* Bb = Xb + (size_t)(c0 + l15) * DIM + quad * 8;

    float dp[4][4], pp[4][4];
    #pragma unroll
    for (int a = 0; a < 4; ++a)
        #pragma unroll
        for (int b = 0; b < 4; ++b) { dp[a][b] = 0.f; pp[a][b] = 0.f; }

    // pos block for this wave's rows = 64-col tile pt; in-group iff cg owns it.
    const int  pt     = R0 >> 6;
    const bool haspos = (pt >= start) && (pt < start + cnt);
    const int  s0     = (pt - start) * 4;    // first of 4 pos steps

    short8 nb[4];
    #pragma unroll
    for (int ko = 0; ko < 4; ++ko)
        nb[ko] = *(const short8*)(Bb + ko * 32);

    #pragma unroll 1
    for (int s = 0; s < nsteps; ++s) {
        short8 cb[4];
        #pragma unroll
        for (int ko = 0; ko < 4; ++ko) cb[ko] = nb[ko];
        if (s + 1 < nsteps) {
            const __hip_bfloat16* p = Bb + (size_t)(s + 1) * 16 * DIM;
            #pragma unroll
            for (int ko = 0; ko < 4; ++ko)
                nb[ko] = *(const short8*)(p + ko * 32);
        }

        floatx4 acc[4];
        #pragma unroll
        for (int mi = 0; mi < 4; ++mi) acc[mi] = (floatx4)0.0f;
        #pragma unroll
        for (int ko = 0; ko < 4; ++ko)
            #pragma unroll
            for (int mi = 0; mi < 4; ++mi)
                acc[mi] = __builtin_amdgcn_mfma_f32_16x16x32_bf16(
                    af[mi][ko], cb[ko], acc[mi], 0, 0, 0);

        // Epilogue: C/D layout col=l15, row=mi*16+quad*4+rg.
        const bool ispos = haspos && (s >= s0) && (s < s0 + 4);  // wave-uniform
        #pragma unroll
        for (int mi = 0; mi < 4; ++mi)
            #pragma unroll
            for (int rg = 0; rg < 4; ++rg) {
                float ev = EXP2F(acc[mi][rg]);
                // diagonal: row_off == col_off -> exact exp(10) (bf16 noise fix)
                if (ispos && mi == s - s0 && l15 == quad * 4 + rg)
                    ev = EXPTEN;
                dp[mi][rg] += ev;
                if (ispos) pp[mi][rg] += ev;
            }
    }

    // Reduce over the 16 col-lanes; plain stores (single writer), no atomics.
    #pragma unroll
    for (int mi = 0; mi < 4; ++mi)
        #pragma unroll
        for (int rg = 0; rg < 4; ++rg) {
            float v = dp[mi][rg];
            #pragma unroll
            for (int m = 1; m < 16; m <<= 1) v += __shfl_xor(v, m);
            if (l15 == 0)
                part[(size_t)cg * N_ROWS + R0 + mi * 16 + quad * 4 + rg] = v;
        }
    if (haspos) {
        #pragma unroll
        for (int mi = 0; mi < 4; ++mi)
            #pragma unroll
            for (int rg = 0; rg < 4; ++rg) {
                float v = pp[mi][rg];
                #pragma unroll
                for (int m = 1; m < 16; m <<= 1) v += __shfl_xor(v, m);
                if (l15 == 0)
                    pos[R0 + mi * 16 + quad * 4 + rg] = v;
            }
    }
}

// ---- Kernel 3: per-row den = sum of 24 partials; block sums of log(den/pos) ----
__global__ void dr_kernel(const float* __restrict__ part, const float* __restrict__ pos,
                          float* __restrict__ bsum) {
    __shared__ float red[4];
    const int row = blockIdx.x * 256 + threadIdx.x;
    float den = 0.f;
    #pragma unroll
    for (int g = 0; g < NGRP; ++g)
        den += part[(size_t)g * N_ROWS + row];   // coalesced across threads
    float v = __logf(den / pos[row]);
    #pragma unroll
    for (int m = 1; m < 64; m <<= 1) v += __shfl_xor(v, m);
    int lane = threadIdx.x & 63, w = threadIdx.x >> 6;
    if (lane == 0) red[w] = v;
    __syncthreads();
    if (threadIdx.x == 0)
        bsum[blockIdx.x] = red[0] + red[1] + red[2] + red[3];
}

// ---- Kernel 4: fold 32 block sums ----
__global__ void loss_kernel(const float* __restrict__ bsum, float* __restrict__ out) {
    float v = (threadIdx.x < 32) ? bsum[threadIdx.x] : 0.f;
    #pragma unroll
    for (int m = 1; m < 64; m <<= 1) v += __shfl_xor(v, m);
    if (threadIdx.x == 0) out[0] = v * (1.0f / (float)N_ROWS);
}

extern "C" void kernel_launch(void* const* d_in, const int* in_sizes, int n_in,
                              void* d_out, int out_size, void* d_ws, size_t ws_size,
                              hipStream_t stream) {
    const float* feature = (const float*)d_in[0];
    // ws: pos[8192] | part[24*8192] | bsum[32] | pad | Xb[8192*128] bf16
    float* pos  = (float*)d_ws;
    float* part = pos + N_ROWS;
    float* bsum = part + (size_t)NGRP * N_ROWS;
    __hip_bfloat16* Xb = (__hip_bfloat16*)(bsum + 64);

    norm_kernel<<<N_ROWS / 4, 256, 0, stream>>>(feature, Xb);
    gram_kernel<<<dim3(32, NGRP), 256, 0, stream>>>(Xb, pos, part);
    dr_kernel<<<N_ROWS / 256, 256, 0, stream>>>(part, pos, bsum);
    loss_kernel<<<1, 64, 0, stream>>>(bsum, (float*)d_out);
}